// Round 12
// baseline (173.281 us; speedup 1.0000x reference)
//
#include <hip/hip_runtime.h>
#include <hip/hip_bf16.h>
#include <math.h>

// Problem constants
#define SEQ 4096
#define DM  1024
#define NIMU 72
#define NNOISE 12
#define NJ (NIMU*NNOISE)     // 864
#define TSTEPS 300
#define PLANE (NIMU*SEQ)     // 294912

// Fragment-linear layouts for mfma_f32_32x32x16_bf16 operands:
//   granule(tile, ch) = 512 shorts (1 KB); lane l holds 8 shorts at +l*8:
//     row (m or n) = l&31, k = ch*16 + (l>>5)*8 + 0..7
//   ch 0..63 = hi half (k 0..1023), ch 64..127 = lo half.
// A2f : 128 s_tiles(32 rows) x 128 ch x 512 shorts = 16.78 MB
// Btf : 28  j_tiles(32 cols) x 128 ch x 512 shorts =  1.83 MB (jt 27 junk)
// pt  : 864 x 4096 f32 = 14.16 MB (planes 0..7 used by spring)
#define A2F_SHORTS ((size_t)128 * 128 * 512)
#define BTF_SHORTS ((size_t)28 * 128 * 512)

typedef __attribute__((ext_vector_type(8)))  short bf16x8;
typedef __attribute__((ext_vector_type(4)))  float f32x4;
typedef __attribute__((ext_vector_type(2)))  float f32x2;
typedef __attribute__((ext_vector_type(16))) float f32x16;

__device__ __forceinline__ float softplus_f(float x) {
    return fmaxf(x, 0.f) + log1pf(expf(-fabsf(x)));
}

// round-to-nearest-even bf16 split: x ~= hi + lo with |err| ~ 2^-16 * |x|
__device__ __forceinline__ void split_bf16(float x, short& hi, short& lo) {
    unsigned b = __float_as_uint(x);
    unsigned h = (b + 0x7FFFu + ((b >> 16) & 1u)) >> 16;
    float hf = __uint_as_float(h << 16);
    float r = x - hf;
    unsigned b2 = __float_as_uint(r);
    unsigned l2 = (b2 + 0x7FFFu + ((b2 >> 16) & 1u)) >> 16;
    hi = (short)h;
    lo = (short)l2;
}

// ---------------- 1. LayerNorm -> A2f (32-row fragment-linear, bf16 hi|lo) ----------------
// Block = one 32-row s_tile. mrow = tid>>3 (0..31), g = tid&7 covers float4 g+8i.
// Row stats via shfl_xor over the 8 g-lanes (masks 1,2,4 — contiguous within wave).
// Offset derivation: k_base = 4g+32i; ch = (g>>2)+2i; granule lane = mrow+32*((g>>1)&1);
// short offset = mrow*8 + 256*((g>>1)&1) + 4*(g&1).
__global__ __launch_bounds__(256) void ln_kernel(const float* __restrict__ x,
                                                 const float* __restrict__ gamma,
                                                 const float* __restrict__ beta,
                                                 short* __restrict__ A2f) {
    const int s_tile = blockIdx.x;
    const int tid = threadIdx.x;
    const int mrow = tid >> 3;
    const int g    = tid & 7;
    const int row  = s_tile * 32 + mrow;
    const float4* xr = (const float4*)(x + (size_t)row * DM);

    float s = 0.f, sq = 0.f;
    #pragma unroll
    for (int i = 0; i < 32; ++i) {
        float4 v = xr[g + 8 * i];
        s  += v.x + v.y + v.z + v.w;
        sq += v.x*v.x + v.y*v.y + v.z*v.z + v.w*v.w;
    }
    #pragma unroll
    for (int off = 1; off < 8; off <<= 1) {
        s  += __shfl_xor(s, off);
        sq += __shfl_xor(sq, off);
    }
    const float mean = s * (1.f / DM);
    const float var  = sq * (1.f / DM) - mean * mean;
    const float rstd = rsqrtf(fmaxf(var, 0.f) + 1e-5f);

    short* tbase = A2f + (size_t)s_tile * (128 * 512)
                 + mrow * 8 + ((g >> 1) & 1) * 256 + (g & 1) * 4;
    #pragma unroll
    for (int i = 0; i < 32; ++i) {
        float4 v  = xr[g + 8 * i];
        float4 gm = ((const float4*)gamma)[g + 8 * i];
        float4 bt = ((const float4*)beta)[g + 8 * i];
        float o[4];
        o[0] = (v.x - mean) * rstd * gm.x + bt.x;
        o[1] = (v.y - mean) * rstd * gm.y + bt.y;
        o[2] = (v.z - mean) * rstd * gm.z + bt.z;
        o[3] = (v.w - mean) * rstd * gm.w + bt.w;
        short4 hv, lv;
        split_bf16(o[0], hv.x, lv.x);
        split_bf16(o[1], hv.y, lv.y);
        split_bf16(o[2], hv.z, lv.z);
        split_bf16(o[3], hv.w, lv.w);
        const int ch = (g >> 2) + 2 * i;
        *(short4*)(tbase + (size_t)ch * 512)              = hv;   // hi
        *(short4*)(tbase + (size_t)(64 + ch) * 512)       = lv;   // lo
    }
}

// ---------------- 2a. W -> Btf (transpose + split, 32-col fragment-linear) ----------------
// Block: 32k x 32j. Stage to LDS, then 4 granules: quad = t>>6 -> {hilo, ch_local}.
__global__ __launch_bounds__(256) void wprep_kernel(const float* __restrict__ W,
                                                    short* __restrict__ Btf) {
    __shared__ float T[32][33];
    const int k0 = blockIdx.x * 32;
    const int jt = blockIdx.y;             // j_tile 0..26
    const int j0 = jt * 32;
    const int t = threadIdx.x;
    {
        const int r = t >> 3, c4 = (t & 7) * 4;
        float4 v = *(const float4*)(W + (size_t)(k0 + r) * NJ + j0 + c4);
        T[r][c4 + 0] = v.x; T[r][c4 + 1] = v.y; T[r][c4 + 2] = v.z; T[r][c4 + 3] = v.w;
    }
    __syncthreads();
    const int quad = t >> 6;               // 0..3: hilo = quad>>1, chl = quad&1
    const int l    = t & 63;
    const int hilo = quad >> 1, chl = quad & 1;
    const int jcol = l & 31, kc = l >> 5;
    bf16x8 ov;
    #pragma unroll
    for (int o = 0; o < 8; ++o) {
        short h, lo_;
        split_bf16(T[16 * chl + 8 * kc + o][jcol], h, lo_);
        ov[o] = hilo ? lo_ : h;
    }
    *(bf16x8*)(Btf + ((size_t)jt * 128 + (k0 >> 4) + chl + 64 * hilo) * 512 + l * 8) = ov;
}

// ---------------- 2b. Barrier-free 32x32-MFMA GEMM + fused tail ----------------
// R11 failure: wave 64x64 (16x16 frags) needed 192 VGPR for reg-dbuf, got 120 ->
// prefetch demoted, ~16 exposed L2 hits/iter, MfmaUtil 18% @ 5.9% occupancy.
// R12: one 32x32 tile per wave (acc 16 VGPR, dbuf 32) -> ~70 VGPR, grid (64,14)
// = 896 blocks x 4 waves = 3584 waves (14/CU). Per 16-k chunk: 4 coalesced
// granule loads, 3 MFMA (hh, hl, lh). Block 2x2 tiles -> A/B 2-way L1 sharing.
// j < 576 -> pt; j >= 576 -> out (softplus on odd planes).
__global__ __launch_bounds__(256) void gemm_kernel(const short* __restrict__ A2f,
                                                   const short* __restrict__ Btf,
                                                   const float* __restrict__ bias,
                                                   float* __restrict__ pt,
                                                   float* __restrict__ out) {
    const int l = threadIdx.x & 63, w = threadIdx.x >> 6;
    const int st = blockIdx.x * 2 + (w & 1);     // s_tile 0..127
    const int jt = blockIdx.y * 2 + (w >> 1);    // j_tile 0..27 (27 junk, guarded)
    const short* aB = A2f + (size_t)st * (128 * 512) + l * 8;
    const short* bB = Btf + (size_t)jt * (128 * 512) + l * 8;

    f32x16 acc = {};
    bf16x8 ah[2], al[2], bh[2], bl[2];

    auto ldstep = [&](int slot, int i) {
        ah[slot] = *(const bf16x8*)(aB + (size_t)i * 512);
        al[slot] = *(const bf16x8*)(aB + (size_t)(64 + i) * 512);
        bh[slot] = *(const bf16x8*)(bB + (size_t)i * 512);
        bl[slot] = *(const bf16x8*)(bB + (size_t)(64 + i) * 512);
    };

    ldstep(0, 0);
    #pragma unroll 4
    for (int i = 0; i < 64; ++i) {
        const int cur = i & 1;
        if (i + 1 < 64) ldstep(cur ^ 1, i + 1);   // next chunk in flight during MFMA
        acc = __builtin_amdgcn_mfma_f32_32x32x16_bf16(ah[cur], bh[cur], acc, 0, 0, 0);
        acc = __builtin_amdgcn_mfma_f32_32x32x16_bf16(ah[cur], bl[cur], acc, 0, 0, 0);
        acc = __builtin_amdgcn_mfma_f32_32x32x16_bf16(al[cur], bh[cur], acc, 0, 0, 0);
    }

    // 32x32 C/D layout [m74/m101]: col(n=j) = lane&31, row(m=s) = (reg&3)+8*(reg>>2)+4*(lane>>5)
    const int j = jt * 32 + (l & 31);
    if (j < NJ) {
        const float bj = bias[j];
        const int sb = st * 32 + 4 * (l >> 5);
        if (j < 8 * NIMU) {
            float* dst = pt + (size_t)j * SEQ + sb;
            #pragma unroll
            for (int rg = 0; rg < 4; ++rg) {
                f32x4 v = {acc[4*rg+0] + bj, acc[4*rg+1] + bj,
                           acc[4*rg+2] + bj, acc[4*rg+3] + bj};
                *(f32x4*)(dst + 8 * rg) = v;
            }
        } else {
            const int q  = (j - 8 * NIMU) / NIMU;          // plane 0..3
            const int im = (j - 8 * NIMU) - NIMU * q;
            float* dst = out + (size_t)(1 + q) * PLANE + (size_t)im * SEQ + sb;
            #pragma unroll
            for (int rg = 0; rg < 4; ++rg) {
                f32x4 v = {acc[4*rg+0] + bj, acc[4*rg+1] + bj,
                           acc[4*rg+2] + bj, acc[4*rg+3] + bj};
                if (q & 1) {
                    v[0] = softplus_f(v[0]); v[1] = softplus_f(v[1]);
                    v[2] = softplus_f(v[2]); v[3] = softplus_f(v[3]);
                }
                *(f32x4*)(dst + 8 * rg) = v;
            }
        }
    }
}

// ---------------- 3. Spring: sliding-window rotate accumulator (unchanged R11) ----------------
__global__ __launch_bounds__(256) void spring_kernel(const float* __restrict__ pt,
                                                     float* __restrict__ kin) {
    const int lane = threadIdx.x & 63;
    const int wid  = threadIdx.x >> 6;
    const int sblk = blockIdx.x * 4 + wid;    // 0..63
    const int imu  = blockIdx.y;
    const int sbase = sblk * 64;
    const int s    = sbase + lane;

    const int base = imu * SEQ + s;
    const float p0  = pt[(size_t)0 * PLANE + base];
    const float p1  = pt[(size_t)1 * PLANE + base];
    const float p2  = pt[(size_t)2 * PLANE + base];
    const float p3  = pt[(size_t)3 * PLANE + base];
    const float c1  = pt[(size_t)4 * PLANE + base];
    const float c2  = pt[(size_t)5 * PLANE + base];
    const float ph1 = pt[(size_t)6 * PLANE + base];
    const float ph2 = pt[(size_t)7 * PLANE + base];

    float dd = softplus_f(p1);
    float kk = dd * dd * 0.25f + softplus_f(p0);
    float om1 = 0.5f * sqrtf(fmaxf(4.f * kk - dd * dd, 0.f));
    float dt = softplus_f(p3);
    float kt = dt * dt * 0.25f + softplus_f(p2);
    float om2 = 0.5f * sqrtf(fmaxf(4.f * kt - dt * dt, 0.f));
    float e1 = expf(-0.5f * dd), e2 = expf(-0.5f * dt);
    float sn, cs, sn2, cs2;
    sincosf(om1, &sn, &cs);
    sincosf(om2, &sn2, &cs2);
    const f32x2 Rr = {e1 * cs, e2 * cs2};
    const f32x2 Ri = {e1 * sn, e2 * sn2};
    sincosf(ph1, &sn, &cs);
    sincosf(ph2, &sn2, &cs2);
    f32x2 zr = {c1 * cs, c2 * cs2};
    f32x2 zi = {c1 * sn, c2 * sn2};

    float a = 0.f;   // sliding accumulator: holds p = sbase + lane + t
    float d = 0.f;   // collector: lane tr holds p = sbase + 64q + tr
    float* kimu = kin + (size_t)imu * SEQ;

    #pragma unroll
    for (int q = 0; q < 5; ++q) {
        const int steps = (q == 4) ? 44 : 64;   // 300 = 4*64 + 44
        #pragma unroll
        for (int tr = 0; tr < steps; ++tr) {
            float v = zi.x + zi.y;
            f32x2 nr = zr * Rr - zi * Ri;
            zi = zr * Ri + zi * Rr;
            zr = nr;
            int as = __builtin_amdgcn_update_dpp(0, __float_as_int(a),
                                                 0x130, 0xF, 0xF, true);  // wave_shl1
            a = __int_as_float(as) + v;
            int u = __builtin_amdgcn_readlane(__float_as_int(a), 0);
            d = (lane == tr) ? __int_as_float(u) : d;
        }
        const int pos = sbase + q * 64 + lane;
        if (pos < SEQ)
            __hip_atomic_fetch_add(kimu + pos, d,
                                   __ATOMIC_RELAXED, __HIP_MEMORY_SCOPE_AGENT);
        d = 0.f;
    }

    if (lane > 0) {
        const int pos = sbase + 299 + lane;
        if (pos < SEQ)
            __hip_atomic_fetch_add(kimu + pos, a,
                                   __ATOMIC_RELAXED, __HIP_MEMORY_SCOPE_AGENT);
    }
}

extern "C" void kernel_launch(void* const* d_in, const int* in_sizes, int n_in,
                              void* d_out, int out_size, void* d_ws, size_t ws_size,
                              hipStream_t stream) {
    const float* hs    = (const float*)d_in[0];
    const float* gamma = (const float*)d_in[1];
    const float* beta  = (const float*)d_in[2];
    const float* W     = (const float*)d_in[3];
    const float* b     = (const float*)d_in[4];
    float* out = (float*)d_out;

    short* A2f = (short*)d_ws;                        // 16.78 MB
    short* Btf = A2f + A2F_SHORTS;                    //  1.83 MB
    float* pt  = (float*)(Btf + BTF_SHORTS);          // 14.16 MB

    (void)hipMemsetAsync(out, 0, (size_t)PLANE * sizeof(float), stream);

    ln_kernel<<<SEQ / 32, 256, 0, stream>>>(hs, gamma, beta, A2f);
    wprep_kernel<<<dim3(DM / 32, 27), 256, 0, stream>>>(W, Btf);
    gemm_kernel<<<dim3(64, 14), 256, 0, stream>>>(A2f, Btf, b, pt, out);
    spring_kernel<<<dim3(16, NIMU), 256, 0, stream>>>(pt, out);
}

// Round 13
// 172.248 us; speedup vs baseline: 1.0060x; 1.0060x over previous
//
#include <hip/hip_runtime.h>
#include <hip/hip_bf16.h>
#include <math.h>

// Problem constants
#define SEQ 4096
#define DM  1024
#define NIMU 72
#define NNOISE 12
#define NJ (NIMU*NNOISE)     // 864
#define TSTEPS 300
#define PLANE (NIMU*SEQ)     // 294912

// Fragment-linear layouts for mfma_f32_32x32x16_bf16 operands:
//   granule(tile, ch) = 512 shorts (1 KB); lane l holds 8 shorts at +l*8:
//     row (m or n) = l&31, k = ch*16 + (l>>5)*8 + 0..7
//   ch 0..63 = hi half (k 0..1023), ch 64..127 = lo half.
// A2f : 128 s_tiles(32 rows) x 128 ch x 512 shorts = 16.78 MB
// Btf : 28  j_tiles(32 cols) x 128 ch x 512 shorts =  3.67 MB (jt 27 junk)
// pt  : 864 x 4096 f32 = 14.16 MB (planes 0..7 used by spring)
#define A2F_SHORTS ((size_t)128 * 128 * 512)
#define BTF_SHORTS ((size_t)28 * 128 * 512)

typedef __attribute__((ext_vector_type(8)))  short bf16x8;
typedef __attribute__((ext_vector_type(4)))  float f32x4;
typedef __attribute__((ext_vector_type(2)))  float f32x2;
typedef __attribute__((ext_vector_type(16))) float f32x16;

__device__ __forceinline__ float softplus_f(float x) {
    return fmaxf(x, 0.f) + log1pf(expf(-fabsf(x)));
}

// round-to-nearest-even bf16 split: x ~= hi + lo with |err| ~ 2^-16 * |x|
__device__ __forceinline__ void split_bf16(float x, short& hi, short& lo) {
    unsigned b = __float_as_uint(x);
    unsigned h = (b + 0x7FFFu + ((b >> 16) & 1u)) >> 16;
    float hf = __uint_as_float(h << 16);
    float r = x - hf;
    unsigned b2 = __float_as_uint(r);
    unsigned l2 = (b2 + 0x7FFFu + ((b2 >> 16) & 1u)) >> 16;
    hi = (short)h;
    lo = (short)l2;
}

// ---------------- 1. LayerNorm -> A2f (32-row fragment-linear, bf16 hi|lo) ----------------
__global__ __launch_bounds__(256) void ln_kernel(const float* __restrict__ x,
                                                 const float* __restrict__ gamma,
                                                 const float* __restrict__ beta,
                                                 short* __restrict__ A2f) {
    const int s_tile = blockIdx.x;
    const int tid = threadIdx.x;
    const int mrow = tid >> 3;
    const int g    = tid & 7;
    const int row  = s_tile * 32 + mrow;
    const float4* xr = (const float4*)(x + (size_t)row * DM);

    float s = 0.f, sq = 0.f;
    #pragma unroll
    for (int i = 0; i < 32; ++i) {
        float4 v = xr[g + 8 * i];
        s  += v.x + v.y + v.z + v.w;
        sq += v.x*v.x + v.y*v.y + v.z*v.z + v.w*v.w;
    }
    #pragma unroll
    for (int off = 1; off < 8; off <<= 1) {
        s  += __shfl_xor(s, off);
        sq += __shfl_xor(sq, off);
    }
    const float mean = s * (1.f / DM);
    const float var  = sq * (1.f / DM) - mean * mean;
    const float rstd = rsqrtf(fmaxf(var, 0.f) + 1e-5f);

    short* tbase = A2f + (size_t)s_tile * (128 * 512)
                 + mrow * 8 + ((g >> 1) & 1) * 256 + (g & 1) * 4;
    #pragma unroll
    for (int i = 0; i < 32; ++i) {
        float4 v  = xr[g + 8 * i];
        float4 gm = ((const float4*)gamma)[g + 8 * i];
        float4 bt = ((const float4*)beta)[g + 8 * i];
        float o[4];
        o[0] = (v.x - mean) * rstd * gm.x + bt.x;
        o[1] = (v.y - mean) * rstd * gm.y + bt.y;
        o[2] = (v.z - mean) * rstd * gm.z + bt.z;
        o[3] = (v.w - mean) * rstd * gm.w + bt.w;
        short4 hv, lv;
        split_bf16(o[0], hv.x, lv.x);
        split_bf16(o[1], hv.y, lv.y);
        split_bf16(o[2], hv.z, lv.z);
        split_bf16(o[3], hv.w, lv.w);
        const int ch = (g >> 2) + 2 * i;
        *(short4*)(tbase + (size_t)ch * 512)              = hv;   // hi
        *(short4*)(tbase + (size_t)(64 + ch) * 512)       = lv;   // lo
    }
}

// ---------------- 2a. W -> Btf (transpose + split, 32-col fragment-linear) ----------------
__global__ __launch_bounds__(256) void wprep_kernel(const float* __restrict__ W,
                                                    short* __restrict__ Btf) {
    __shared__ float T[32][33];
    const int k0 = blockIdx.x * 32;
    const int jt = blockIdx.y;             // j_tile 0..26
    const int j0 = jt * 32;
    const int t = threadIdx.x;
    {
        const int r = t >> 3, c4 = (t & 7) * 4;
        float4 v = *(const float4*)(W + (size_t)(k0 + r) * NJ + j0 + c4);
        T[r][c4 + 0] = v.x; T[r][c4 + 1] = v.y; T[r][c4 + 2] = v.z; T[r][c4 + 3] = v.w;
    }
    __syncthreads();
    const int quad = t >> 6;               // 0..3: hilo = quad>>1, chl = quad&1
    const int l    = t & 63;
    const int hilo = quad >> 1, chl = quad & 1;
    const int jcol = l & 31, kc = l >> 5;
    bf16x8 ov;
    #pragma unroll
    for (int o = 0; o < 8; ++o) {
        short h, lo_;
        split_bf16(T[16 * chl + 8 * kc + o][jcol], h, lo_);
        ov[o] = hilo ? lo_ : h;
    }
    *(bf16x8*)(Btf + ((size_t)jt * 128 + (k0 >> 4) + chl + 64 * hilo) * 512 + l * 8) = ov;
}

// ---------------- 2b. Barrier-free 32x32-MFMA GEMM, 32x64 wave tile ----------------
// R12 post-mortem: 32x32 wave tile = 4 KB loaded per 3 MFMA -> ~170 B/cyc/CU
// operand-stream demand vs ~64 B/cyc L1 -> BW-bound at 46us regardless of
// occupancy. R13: each wave keeps TWO j-tiles (6 KB per 6 MFMA, FLOP/B 24->48)
// and the block's 4 waves share one jt-pair (B granules L1-hit 4-way, B L2
// traffic /4). Grid (32,14) = 448 blocks, 7 waves/CU, ~90 VGPR.
// j < 576 -> pt; j >= 576 -> out (softplus on odd planes).
__global__ __launch_bounds__(256) void gemm_kernel(const short* __restrict__ A2f,
                                                   const short* __restrict__ Btf,
                                                   const float* __restrict__ bias,
                                                   float* __restrict__ pt,
                                                   float* __restrict__ out) {
    const int l = threadIdx.x & 63, w = threadIdx.x >> 6;
    const int st  = blockIdx.x * 4 + w;          // s_tile 0..127 (wave-private A)
    const int jt0 = blockIdx.y * 2;              // j_tile pair (block-shared B)
    const short* aB  = A2f + (size_t)st * (128 * 512) + l * 8;
    const short* bB0 = Btf + (size_t)jt0 * (128 * 512) + l * 8;
    const short* bB1 = Btf + (size_t)(jt0 + 1) * (128 * 512) + l * 8;

    f32x16 acc0 = {}, acc1 = {};
    bf16x8 ah[2], al[2], bh0[2], bl0[2], bh1[2], bl1[2];

    auto ldstep = [&](int slot, int i) {
        ah[slot]  = *(const bf16x8*)(aB  + (size_t)i * 512);
        al[slot]  = *(const bf16x8*)(aB  + (size_t)(64 + i) * 512);
        bh0[slot] = *(const bf16x8*)(bB0 + (size_t)i * 512);
        bl0[slot] = *(const bf16x8*)(bB0 + (size_t)(64 + i) * 512);
        bh1[slot] = *(const bf16x8*)(bB1 + (size_t)i * 512);
        bl1[slot] = *(const bf16x8*)(bB1 + (size_t)(64 + i) * 512);
    };

    ldstep(0, 0);
    #pragma unroll 4
    for (int i = 0; i < 64; ++i) {
        const int cur = i & 1;
        if (i + 1 < 64) ldstep(cur ^ 1, i + 1);   // next chunk in flight during MFMA
        acc0 = __builtin_amdgcn_mfma_f32_32x32x16_bf16(ah[cur], bh0[cur], acc0, 0, 0, 0);
        acc1 = __builtin_amdgcn_mfma_f32_32x32x16_bf16(ah[cur], bh1[cur], acc1, 0, 0, 0);
        acc0 = __builtin_amdgcn_mfma_f32_32x32x16_bf16(ah[cur], bl0[cur], acc0, 0, 0, 0);
        acc1 = __builtin_amdgcn_mfma_f32_32x32x16_bf16(ah[cur], bl1[cur], acc1, 0, 0, 0);
        acc0 = __builtin_amdgcn_mfma_f32_32x32x16_bf16(al[cur], bh0[cur], acc0, 0, 0, 0);
        acc1 = __builtin_amdgcn_mfma_f32_32x32x16_bf16(al[cur], bh1[cur], acc1, 0, 0, 0);
    }

    // 32x32 C/D layout [m74/m101]: col(n=j) = lane&31, row(m=s) = (reg&3)+8*(reg>>2)+4*(lane>>5)
    const int sb = st * 32 + 4 * (l >> 5);
    #pragma unroll
    for (int half = 0; half < 2; ++half) {
        const f32x16& acc = half ? acc1 : acc0;
        const int j = (jt0 + half) * 32 + (l & 31);
        if (j < NJ) {
            const float bj = bias[j];
            if (j < 8 * NIMU) {
                float* dst = pt + (size_t)j * SEQ + sb;
                #pragma unroll
                for (int rg = 0; rg < 4; ++rg) {
                    f32x4 v = {acc[4*rg+0] + bj, acc[4*rg+1] + bj,
                               acc[4*rg+2] + bj, acc[4*rg+3] + bj};
                    *(f32x4*)(dst + 8 * rg) = v;
                }
            } else {
                const int q  = (j - 8 * NIMU) / NIMU;          // plane 0..3
                const int im = (j - 8 * NIMU) - NIMU * q;
                float* dst = out + (size_t)(1 + q) * PLANE + (size_t)im * SEQ + sb;
                #pragma unroll
                for (int rg = 0; rg < 4; ++rg) {
                    f32x4 v = {acc[4*rg+0] + bj, acc[4*rg+1] + bj,
                               acc[4*rg+2] + bj, acc[4*rg+3] + bj};
                    if (q & 1) {
                        v[0] = softplus_f(v[0]); v[1] = softplus_f(v[1]);
                        v[2] = softplus_f(v[2]); v[3] = softplus_f(v[3]);
                    }
                    *(f32x4*)(dst + 8 * rg) = v;
                }
            }
        }
    }
}

// ---------------- 3. Spring: sliding-window rotate accumulator (unchanged R11) ----------------
__global__ __launch_bounds__(256) void spring_kernel(const float* __restrict__ pt,
                                                     float* __restrict__ kin) {
    const int lane = threadIdx.x & 63;
    const int wid  = threadIdx.x >> 6;
    const int sblk = blockIdx.x * 4 + wid;    // 0..63
    const int imu  = blockIdx.y;
    const int sbase = sblk * 64;
    const int s    = sbase + lane;

    const int base = imu * SEQ + s;
    const float p0  = pt[(size_t)0 * PLANE + base];
    const float p1  = pt[(size_t)1 * PLANE + base];
    const float p2  = pt[(size_t)2 * PLANE + base];
    const float p3  = pt[(size_t)3 * PLANE + base];
    const float c1  = pt[(size_t)4 * PLANE + base];
    const float c2  = pt[(size_t)5 * PLANE + base];
    const float ph1 = pt[(size_t)6 * PLANE + base];
    const float ph2 = pt[(size_t)7 * PLANE + base];

    float dd = softplus_f(p1);
    float kk = dd * dd * 0.25f + softplus_f(p0);
    float om1 = 0.5f * sqrtf(fmaxf(4.f * kk - dd * dd, 0.f));
    float dt = softplus_f(p3);
    float kt = dt * dt * 0.25f + softplus_f(p2);
    float om2 = 0.5f * sqrtf(fmaxf(4.f * kt - dt * dt, 0.f));
    float e1 = expf(-0.5f * dd), e2 = expf(-0.5f * dt);
    float sn, cs, sn2, cs2;
    sincosf(om1, &sn, &cs);
    sincosf(om2, &sn2, &cs2);
    const f32x2 Rr = {e1 * cs, e2 * cs2};
    const f32x2 Ri = {e1 * sn, e2 * sn2};
    sincosf(ph1, &sn, &cs);
    sincosf(ph2, &sn2, &cs2);
    f32x2 zr = {c1 * cs, c2 * cs2};
    f32x2 zi = {c1 * sn, c2 * sn2};

    float a = 0.f;   // sliding accumulator: holds p = sbase + lane + t
    float d = 0.f;   // collector: lane tr holds p = sbase + 64q + tr
    float* kimu = kin + (size_t)imu * SEQ;

    #pragma unroll
    for (int q = 0; q < 5; ++q) {
        const int steps = (q == 4) ? 44 : 64;   // 300 = 4*64 + 44
        #pragma unroll
        for (int tr = 0; tr < steps; ++tr) {
            float v = zi.x + zi.y;
            f32x2 nr = zr * Rr - zi * Ri;
            zi = zr * Ri + zi * Rr;
            zr = nr;
            int as = __builtin_amdgcn_update_dpp(0, __float_as_int(a),
                                                 0x130, 0xF, 0xF, true);  // wave_shl1
            a = __int_as_float(as) + v;
            int u = __builtin_amdgcn_readlane(__float_as_int(a), 0);
            d = (lane == tr) ? __int_as_float(u) : d;
        }
        const int pos = sbase + q * 64 + lane;
        if (pos < SEQ)
            __hip_atomic_fetch_add(kimu + pos, d,
                                   __ATOMIC_RELAXED, __HIP_MEMORY_SCOPE_AGENT);
        d = 0.f;
    }

    if (lane > 0) {
        const int pos = sbase + 299 + lane;
        if (pos < SEQ)
            __hip_atomic_fetch_add(kimu + pos, a,
                                   __ATOMIC_RELAXED, __HIP_MEMORY_SCOPE_AGENT);
    }
}

extern "C" void kernel_launch(void* const* d_in, const int* in_sizes, int n_in,
                              void* d_out, int out_size, void* d_ws, size_t ws_size,
                              hipStream_t stream) {
    const float* hs    = (const float*)d_in[0];
    const float* gamma = (const float*)d_in[1];
    const float* beta  = (const float*)d_in[2];
    const float* W     = (const float*)d_in[3];
    const float* b     = (const float*)d_in[4];
    float* out = (float*)d_out;

    short* A2f = (short*)d_ws;                        // 16.78 MB
    short* Btf = A2f + A2F_SHORTS;                    //  3.67 MB
    float* pt  = (float*)(Btf + BTF_SHORTS);          // 14.16 MB

    (void)hipMemsetAsync(out, 0, (size_t)PLANE * sizeof(float), stream);

    ln_kernel<<<SEQ / 32, 256, 0, stream>>>(hs, gamma, beta, A2f);
    wprep_kernel<<<dim3(DM / 32, 27), 256, 0, stream>>>(W, Btf);
    gemm_kernel<<<dim3(32, 14), 256, 0, stream>>>(A2f, Btf, b, pt, out);
    spring_kernel<<<dim3(16, NIMU), 256, 0, stream>>>(pt, out);
}